// Round 17
// baseline (122.176 us; speedup 1.0000x reference)
//
#include <hip/hip_runtime.h>

#define N 4096
#define F 64
#define H 8
#define W1S (2 * F + 1)   // 129
#define PCH 32            // partial chunks (128 rows each)
#define NBLK 1024

typedef float f4 __attribute__((ext_vector_type(4)));

// Tiny counter-zeroer (node 1): 4-byte write, negligible boundary.
__global__ void zcnt(unsigned* __restrict__ cnt) {
    if (threadIdx.x == 0) *cnt = 0;
}

// ---------------------------------------------------------------------------
// Single fused kernel, 1024 blocks x 256 = 4 blocks/CU co-resident.
// Phase 1a (colsum): block b -> chunk ch=b>>5 (128 rows), stripe st=b&31
//   (128 cols). Thread: col=st*128+(t&127), half=t>>7 -> 64 rows, 4-wide
//   pipelined scalar loads -> LDS combine -> partial[ch][col].
// Phase 1b (MLP slice): 4 rows n0=b*4..+3. Thread (f=t>>2, dn=t&3):
//   e=emb[f][n0+dn]; pa[k]=e*W1a[k][f], pb[k]=e*W1b[k][f]; shfl_xor tree
//   over f within wave (masks 4..32), cross-wave via LDS; t<32 finalize
//   aj[n][k], bkF[k][n]; t<4: diag[n]=A[n][n].
// Global barrier: release-add + relaxed spin + acquire-load (agent scope).
// Phase 2 (R13 fuse, verbatim): tile j0=(b&15)*256, i0=(b>>4)*64;
//   stage bks[8][260] in LDS; phase B streams 16 rows x 4 cols/thread,
//   1KB/wave contiguous f4 stores.
// ---------------------------------------------------------------------------
__global__ __launch_bounds__(256, 4) void fused(
    const float* __restrict__ A, const float* __restrict__ emb,
    const float* __restrict__ W1, const float* __restrict__ b1,
    const float* __restrict__ W2, const float* __restrict__ b2,
    unsigned* __restrict__ cnt, float* __restrict__ partial,
    float* __restrict__ aj, float* __restrict__ bkF,
    float* __restrict__ diag, float* __restrict__ out)
{
    __shared__ float ps[2][128];
    __shared__ float mlpA[4][4][H];
    __shared__ float mlpB[4][4][H];
    __shared__ float bks[H][260];

    const int b = blockIdx.x;
    const int t = threadIdx.x;

    // ---- Phase 1a: colsum slice ----
    {
        int ch = b >> 5, st = b & 31;
        int col = st * 128 + (t & 127);
        int half = t >> 7;
        const float* p = A + (size_t)(ch * 128 + half * 64) * N + col;
        float s0 = 0.f, s1 = 0.f, s2 = 0.f, s3 = 0.f;
#pragma unroll 8
        for (int r = 0; r < 64; r += 4) {
            s0 += p[(size_t)(r + 0) * N];
            s1 += p[(size_t)(r + 1) * N];
            s2 += p[(size_t)(r + 2) * N];
            s3 += p[(size_t)(r + 3) * N];
        }
        ps[half][t & 127] = (s0 + s1) + (s2 + s3);
    }

    // ---- Phase 1b: MLP slice for rows/cols n0..n0+3 ----
    const int n0 = b * 4;
    {
        int f = t >> 2, dn = t & 3;
        float e = emb[(size_t)f * N + n0 + dn];
        float pa[H], pb[H];
#pragma unroll
        for (int k = 0; k < H; ++k) {
            pa[k] = e * W1[k * W1S + f];
            pb[k] = e * W1[k * W1S + F + f];
        }
#pragma unroll
        for (int m = 4; m < 64; m <<= 1) {
#pragma unroll
            for (int k = 0; k < H; ++k) {
                pa[k] += __shfl_xor(pa[k], m);
                pb[k] += __shfl_xor(pb[k], m);
            }
        }
        int w = t >> 6, l = t & 63;
        if (l < 4) {
#pragma unroll
            for (int k = 0; k < H; ++k) { mlpA[w][l][k] = pa[k]; mlpB[w][l][k] = pb[k]; }
        }
    }
    __syncthreads();

    if (t < 128) {
        int ch = b >> 5, st = b & 31;
        partial[(size_t)ch * N + st * 128 + t] = ps[0][t] + ps[1][t];
    } else if (t < 160) {
        int u = t - 128;            // 0..31
        int dn = u >> 3, k = u & 7;
        float sa = mlpA[0][dn][k] + mlpA[1][dn][k] + mlpA[2][dn][k] + mlpA[3][dn][k];
        float sb = mlpB[0][dn][k] + mlpB[1][dn][k] + mlpB[2][dn][k] + mlpB[3][dn][k];
        aj[(n0 + dn) * H + k] = b1[k] + sa;
        bkF[(size_t)k * N + n0 + dn] = sb;
    } else if (t < 164) {
        int dn = t - 160;
        diag[n0 + dn] = A[(size_t)(n0 + dn) * (N + 1)];
    }
    __syncthreads();   // drains all vmcnt before barrier arrival

    // ---- Global barrier (agent-scoped, one wbl2+invl2 per block) ----
    if (t == 0) {
        __hip_atomic_fetch_add(cnt, 1u, __ATOMIC_RELEASE, __HIP_MEMORY_SCOPE_AGENT);
        while (__hip_atomic_load(cnt, __ATOMIC_RELAXED, __HIP_MEMORY_SCOPE_AGENT)
               < (unsigned)NBLK)
            __builtin_amdgcn_s_sleep(2);
        (void)__hip_atomic_load(cnt, __ATOMIC_ACQUIRE, __HIP_MEMORY_SCOPE_AGENT);
    }
    __syncthreads();

    // ---- Phase 2: R13 fuse body ----
    const int j0 = (b & 15) * 256;
    const int i0 = (b >> 4) * 64;

    {
        int j = j0 + t;
        float s = 0.f;
        const float* pp = partial + j;
#pragma unroll
        for (int ch = 0; ch < PCH; ++ch) s += pp[(size_t)ch * N];
        float sw = (s - diag[j]) * (1.0f / (float)(N - 1));
#pragma unroll
        for (int k = 0; k < H; ++k)
            bks[k][t] = bkF[(size_t)k * N + j] + sw * W1[k * W1S + 2 * F];
    }
    __syncthreads();

    const int tx = t & 63;
    const int ty = t >> 6;

    f4 bk4[H];
#pragma unroll
    for (int k = 0; k < H; ++k) bk4[k] = *(const f4*)&bks[k][tx * 4];

    float w2[H];
#pragma unroll
    for (int k = 0; k < H; ++k) w2[k] = W2[k];   // W2[0][k]
    const float b20 = b2[0];

    const int j = j0 + tx * 4;
#pragma unroll
    for (int r = 0; r < 16; ++r) {
        int i = i0 + ty * 16 + r;
        f4 alo = *(const f4*)(aj + (size_t)i * H);      // wave-uniform addr
        f4 ahi = *(const f4*)(aj + (size_t)i * H + 4);
        float a[H] = {alo.x, alo.y, alo.z, alo.w, ahi.x, ahi.y, ahi.z, ahi.w};

        f4 res = {b20, b20, b20, b20};
#pragma unroll
        for (int k = 0; k < H; ++k) {
            f4 tt = bk4[k];
            tt.x = fmaxf(a[k] + tt.x, 0.f);
            tt.y = fmaxf(a[k] + tt.y, 0.f);
            tt.z = fmaxf(a[k] + tt.z, 0.f);
            tt.w = fmaxf(a[k] + tt.w, 0.f);
            res.x += tt.x * w2[k];
            res.y += tt.y * w2[k];
            res.z += tt.z * w2[k];
            res.w += tt.w * w2[k];
        }
        *(f4*)(out + (size_t)i * N + j) = res;
    }
}

extern "C" void kernel_launch(void* const* d_in, const int* in_sizes, int n_in,
                              void* d_out, int out_size, void* d_ws, size_t ws_size,
                              hipStream_t stream) {
    const float* adj = (const float*)d_in[0];   // (1, N, N)
    const float* emb = (const float*)d_in[1];   // (1, F, N)
    const float* W1  = (const float*)d_in[2];   // (H, 2F+1)
    const float* b1  = (const float*)d_in[3];   // (H,)
    const float* W2  = (const float*)d_in[4];   // (8, H)
    const float* b2  = (const float*)d_in[5];   // (8,)
    float* out = (float*)d_out;

    unsigned* cnt  = (unsigned*)d_ws;
    float* partial = (float*)((char*)d_ws + 256);   // 32*4096 floats = 512 KB
    float* aj   = partial + (size_t)PCH * N;        // N*H floats = 128 KB
    float* bkF  = aj + (size_t)N * H;               // H*N floats = 128 KB
    float* diag = bkF + (size_t)H * N;              // N floats = 16 KB

    zcnt<<<dim3(1), 64, 0, stream>>>(cnt);
    fused<<<dim3(NBLK), 256, 0, stream>>>(adj, emb, W1, b1, W2, b2,
                                          cnt, partial, aj, bkF, diag, out);
}

// Round 18
// 33.963 us; speedup vs baseline: 3.5973x; 3.5973x over previous
//
#include <hip/hip_runtime.h>

#define N 4096
#define F 64
#define H 8
#define W1S (2 * F + 1)   // 129
#define PCH 64            // partial chunks (64 rows each)

typedef float f4 __attribute__((ext_vector_type(4)));

// ---------------------------------------------------------------------------
// K1 "prep": 1056 blocks x 256. No atomics, no memset.
//  blocks 0-1023: column sums of A -> partial[64][4096].
//    block b: stripe st=b&15 (256 cols), chunk ch=b>>4 (64 rows).
//    thread t -> col j=st*256+t, scalar loads (block reads 1KB/row),
//    64 independent loads pipelined 4-wide. 4 blocks/CU.
//  blocks 1024-1039: aj[n][8]  = b1 + E.W1a      (running accum, low VGPR)
//  blocks 1040-1055: bkF_T[k][n] = sum_f E.W1b   (coalesced per-k stores)
//                    + diag[n] = A[n][n]
// ---------------------------------------------------------------------------
__global__ __launch_bounds__(256) void prep(const float* __restrict__ A,
                                            const float* __restrict__ emb,
                                            const float* __restrict__ W1,
                                            const float* __restrict__ b1,
                                            float* __restrict__ partial,
                                            float* __restrict__ aj,
                                            float* __restrict__ bkF,
                                            float* __restrict__ diag) {
    const int b = blockIdx.x;
    const int t = threadIdx.x;

    if (b < 1024) {
        int st = b & 15;
        int ch = b >> 4;
        int j  = st * 256 + t;
        const float* p = A + (size_t)(ch * 64) * N + j;
        float s0 = 0.f, s1 = 0.f, s2 = 0.f, s3 = 0.f;
#pragma unroll 8
        for (int r = 0; r < 64; r += 4) {
            s0 += p[(size_t)(r + 0) * N];
            s1 += p[(size_t)(r + 1) * N];
            s2 += p[(size_t)(r + 2) * N];
            s3 += p[(size_t)(r + 3) * N];
        }
        partial[(size_t)ch * N + j] = (s0 + s1) + (s2 + s3);
    } else {
        int idx = b - 1024;                // 0..31
        int n = (idx & 15) * 256 + t;
        if (idx < 16) {
            float av[H];
#pragma unroll
            for (int k = 0; k < H; ++k) av[k] = b1[k];
#pragma unroll
            for (int f = 0; f < F; ++f) {
                float e = emb[(size_t)f * N + n];
#pragma unroll
                for (int k = 0; k < H; ++k) av[k] += e * W1[k * W1S + f];
            }
#pragma unroll
            for (int k = 0; k < H; ++k) aj[n * H + k] = av[k];
        } else {
            float bv[H];
#pragma unroll
            for (int k = 0; k < H; ++k) bv[k] = 0.f;
#pragma unroll
            for (int f = 0; f < F; ++f) {
                float e = emb[(size_t)f * N + n];
#pragma unroll
                for (int k = 0; k < H; ++k) bv[k] += e * W1[k * W1S + F + f];
            }
#pragma unroll
            for (int k = 0; k < H; ++k) bkF[(size_t)k * N + n] = bv[k];
            diag[n] = A[(size_t)n * N + n];
        }
    }
}

// ---------------------------------------------------------------------------
// K2 "fuse": grid (16,64) = 1024 blocks, tile 256 cols x 64 rows.
// Byte-identical to R14 (best measured) except PCH loop = 64.
// Phase A: thread t -> col j=j0+t: s = sum_{ch<64} partial[ch][j];
//          sw = (s - diag[j])/4095;
//          bks[k][t] = bkF_T[k][j] + sw*W1[k][128]   (LDS [8][260])
// Phase B: tx=t&63 -> 4 cols (bk4 regs), ty=t>>6 -> 16 rows; aj loads
//          wave-uniform broadcast; float4 stores 1KB/wave contiguous.
// ---------------------------------------------------------------------------
__global__ __launch_bounds__(256, 8) void fuse(const float* __restrict__ W1,
                                               const float* __restrict__ aj,
                                               const float* __restrict__ bkF,
                                               const float* __restrict__ partial,
                                               const float* __restrict__ diag,
                                               const float* __restrict__ W2,
                                               const float* __restrict__ b2,
                                               float* __restrict__ out) {
    __shared__ float bks[H][260];          // 1040B row stride, 16B-aligned

    const int t  = threadIdx.x;
    const int j0 = blockIdx.x * 256;
    const int i0 = blockIdx.y * 64;

    {
        int j = j0 + t;
        float s = 0.f;
        const float* pp = partial + j;
#pragma unroll 16
        for (int ch = 0; ch < PCH; ++ch) s += pp[(size_t)ch * N];
        float sw = (s - diag[j]) * (1.0f / (float)(N - 1));
#pragma unroll
        for (int k = 0; k < H; ++k)
            bks[k][t] = bkF[(size_t)k * N + j] + sw * W1[k * W1S + 2 * F];
    }
    __syncthreads();

    const int tx = t & 63;
    const int ty = __builtin_amdgcn_readfirstlane(t >> 6);

    f4 bk4[H];
#pragma unroll
    for (int k = 0; k < H; ++k) bk4[k] = *(const f4*)&bks[k][tx * 4];

    float w2[H];
#pragma unroll
    for (int k = 0; k < H; ++k) w2[k] = W2[k];   // W2[0][k]
    const float b20 = b2[0];

    const int j = j0 + tx * 4;
#pragma unroll
    for (int r = 0; r < 16; ++r) {
        int i = i0 + ty * 16 + r;
        f4 alo = *(const f4*)(aj + (size_t)i * H);      // wave-uniform addr
        f4 ahi = *(const f4*)(aj + (size_t)i * H + 4);
        float a[H] = {alo.x, alo.y, alo.z, alo.w, ahi.x, ahi.y, ahi.z, ahi.w};

        f4 res = {b20, b20, b20, b20};
#pragma unroll
        for (int k = 0; k < H; ++k) {
            f4 tt = bk4[k];
            tt.x = fmaxf(a[k] + tt.x, 0.f);
            tt.y = fmaxf(a[k] + tt.y, 0.f);
            tt.z = fmaxf(a[k] + tt.z, 0.f);
            tt.w = fmaxf(a[k] + tt.w, 0.f);
            res.x += tt.x * w2[k];
            res.y += tt.y * w2[k];
            res.z += tt.z * w2[k];
            res.w += tt.w * w2[k];
        }
        *(f4*)(out + (size_t)i * N + j) = res;
    }
}

extern "C" void kernel_launch(void* const* d_in, const int* in_sizes, int n_in,
                              void* d_out, int out_size, void* d_ws, size_t ws_size,
                              hipStream_t stream) {
    const float* adj = (const float*)d_in[0];   // (1, N, N)
    const float* emb = (const float*)d_in[1];   // (1, F, N)
    const float* W1  = (const float*)d_in[2];   // (H, 2F+1)
    const float* b1  = (const float*)d_in[3];   // (H,)
    const float* W2  = (const float*)d_in[4];   // (8, H)
    const float* b2  = (const float*)d_in[5];   // (8,)
    float* out = (float*)d_out;

    float* partial = (float*)d_ws;              // 64*4096 floats = 1 MB
    float* aj   = partial + (size_t)PCH * N;    // N*H floats = 128 KB
    float* bkF  = aj + (size_t)N * H;           // H*N floats = 128 KB
    float* diag = bkF + (size_t)H * N;          // N floats = 16 KB

    prep<<<dim3(1056), 256, 0, stream>>>(adj, emb, W1, b1, partial, aj, bkF, diag);
    fuse<<<dim3(N / 256, N / 64), 256, 0, stream>>>(W1, aj, bkF, partial, diag,
                                                    W2, b2, out);
}